// Round 12
// baseline (185.998 us; speedup 1.0000x reference)
//
#include <hip/hip_runtime.h>
#include <math.h>
#include <stdint.h>

// out_i = clamp(out_{i-1}; a_i, a_i+1), a_i = x_i * k.  Clamp functions
// p -> min(max(p,lo),hi) compose associatively -> parallel scan.
//
// R12: single dispatch, software grid barrier, but with the R11 lesson
// applied: R11's grid=256 gave 4 waves/CU (Occupancy 10.7%, hbm 900 GB/s,
// VALUBusy 11% -> latency-bound). Now 1024 blocks = 4 blocks/CU
// (capacity-guaranteed by __launch_bounds__(256,4): 16 waves/CU of 32),
// and each block's 8192-elem chunk lives in 32 VGPRs ACROSS the barrier,
// eliminating the phase-3 re-read (33.5 MB less traffic than R11).

#define TPB 256
#define WAVES 4
#define SEGS 4
#define FPL 8
#define SEG_ELEMS (TPB * FPL)            // 2048
#define BLK_ELEMS (SEGS * SEG_ELEMS)     // 8192 -> 1024 blocks @ T=2^23

typedef float v4f __attribute__((ext_vector_type(4)));

__device__ __forceinline__ float clampf(float x, float lo, float hi) {
    return fminf(fmaxf(x, lo), hi);
}
__device__ __forceinline__ uint64_t pack2(float lo, float hi) {
    union { float f[2]; uint64_t u; } u; u.f[0] = lo; u.f[1] = hi; return u.u;
}
__device__ __forceinline__ void unpack2(uint64_t w, float* lo, float* hi) {
    union { uint64_t u; float f[2]; } u; u.u = w; *lo = u.f[0]; *hi = u.f[1];
}

__global__ __launch_bounds__(TPB, 4) void phi_scan(
    const v4f* __restrict__ x4,
    const float* __restrict__ kern,
    const float* __restrict__ state,
    float* __restrict__ out,           // T outputs + 1 new_state
    uint64_t* __restrict__ agg,        // [nblocks] packed (lo,hi)
    uint32_t* __restrict__ counter,
    int nblocks)
{
    __shared__ float wl[SEGS][WAVES], wh[SEGS][WAVES];
    __shared__ float rl[WAVES], rh[WAVES];
    __shared__ float s_v;

    const int t = threadIdx.x, lane = t & 63, w = t >> 6;
    const int b = blockIdx.x;
    const float k = kern[0];
    const size_t blk4 = (size_t)b * (BLK_ELEMS / 4);

    // ---- phase 1: load x into registers, full block-local scan machinery ----
    float a[SEGS][FPL];                 // 32 VGPRs, live across the barrier
    float eslo[SEGS], eshi[SEGS];       // thread-exclusive prefix per segment
    float Slo[SEGS], Shi[SEGS];         // segment totals

#pragma unroll
    for (int s = 0; s < SEGS; ++s) {
        const size_t i4 = blk4 + (size_t)s * (SEG_ELEMS / 4) + (size_t)t * 2;
        v4f v0 = __builtin_nontemporal_load(&x4[i4]);   // only use of x
        v4f v1 = __builtin_nontemporal_load(&x4[i4 + 1]);
        a[s][0] = v0.x * k; a[s][1] = v0.y * k; a[s][2] = v0.z * k; a[s][3] = v0.w * k;
        a[s][4] = v1.x * k; a[s][5] = v1.y * k; a[s][6] = v1.z * k; a[s][7] = v1.w * k;
        float lo = a[s][0], hi = a[s][0] + 1.0f;
#pragma unroll
        for (int j = 1; j < FPL; ++j) {
            lo = clampf(lo, a[s][j], a[s][j] + 1.0f);
            hi = clampf(hi, a[s][j], a[s][j] + 1.0f);
        }
        // wave inclusive scan on lane pairs (prefix FIRST, self SECOND)
#pragma unroll
        for (int off = 1; off < 64; off <<= 1) {
            float plo = __shfl_up(lo, off);
            float phi_ = __shfl_up(hi, off);
            if (lane >= off) {
                float nlo = clampf(plo, lo, hi);
                float nhi = clampf(phi_, lo, hi);
                lo = nlo; hi = nhi;
            }
        }
        float elo = __shfl_up(lo, 1), ehi = __shfl_up(hi, 1);
        if (lane == 0) { elo = -INFINITY; ehi = INFINITY; }
        eslo[s] = elo; eshi[s] = ehi;
        if (lane == 63) { wl[s][w] = lo; wh[s][w] = hi; }
    }
    __syncthreads();

#pragma unroll
    for (int s = 0; s < SEGS; ++s) {
        float welo = -INFINITY, wehi = INFINITY;   // earlier waves in segment
        for (int i = 0; i < w; ++i) {
            welo = clampf(welo, wl[s][i], wh[s][i]);
            wehi = clampf(wehi, wl[s][i], wh[s][i]);
        }
        float llo = eslo[s], lhi = eshi[s];
        eslo[s] = clampf(welo, llo, lhi);          // compose(waves-bef, lanes-bef)
        eshi[s] = clampf(wehi, llo, lhi);
        float stl = -INFINITY, sth = INFINITY;     // segment total
#pragma unroll
        for (int i = 0; i < WAVES; ++i) {
            stl = clampf(stl, wl[s][i], wh[s][i]);
            sth = clampf(sth, wl[s][i], wh[s][i]);
        }
        Slo[s] = stl; Shi[s] = sth;
    }

    // ---- publish aggregate + grid barrier (one-shot, near-equal arrival) ----
    if (t == 0) {
        float Alo = -INFINITY, Ahi = INFINITY;
#pragma unroll
        for (int s = 0; s < SEGS; ++s) {
            Alo = clampf(Alo, Slo[s], Shi[s]);
            Ahi = clampf(Ahi, Slo[s], Shi[s]);
        }
        __hip_atomic_store(&agg[b], pack2(Alo, Ahi),
                           __ATOMIC_RELEASE, __HIP_MEMORY_SCOPE_AGENT);
        __hip_atomic_fetch_add(counter, 1u,
                               __ATOMIC_RELEASE, __HIP_MEMORY_SCOPE_AGENT);
        while (__hip_atomic_load(counter, __ATOMIC_ACQUIRE,
                                 __HIP_MEMORY_SCOPE_AGENT) < (uint32_t)nblocks)
            __builtin_amdgcn_s_sleep(16);
    }
    __syncthreads();

    // ---- phase 2: block entry value from agg[0..b-1] (R8 part A) ----
    {
        const int per = nblocks / TPB;   // 4
        float lo = -INFINITY, hi = INFINITY;
#pragma unroll
        for (int c = 0; c < per; ++c) {
            int j = t * per + c;
            if (j < b) {
                float l, h;
                unpack2(__hip_atomic_load(&agg[j], __ATOMIC_RELAXED,
                                          __HIP_MEMORY_SCOPE_AGENT), &l, &h);
                lo = clampf(lo, l, h);
                hi = clampf(hi, l, h);
            }
        }
#pragma unroll
        for (int off = 1; off < 64; off <<= 1) {
            float plo = __shfl_down(lo, off);
            float phi_ = __shfl_down(hi, off);
            float nlo = clampf(lo, plo, phi_);
            float nhi = clampf(hi, plo, phi_);
            lo = nlo; hi = nhi;
        }
        if (lane == 0) { rl[w] = lo; rh[w] = hi; }
        __syncthreads();
        if (t == 0) {
            float L = rl[0], H = rh[0];
#pragma unroll
            for (int i = 1; i < WAVES; ++i) {
                L = clampf(L, rl[i], rh[i]);
                H = clampf(H, rl[i], rh[i]);
            }
            s_v = clampf(state[0], L, H);       // block entry VALUE
        }
        __syncthreads();
    }

    // ---- phase 3: apply from registers, NT stores ----
    float p = s_v;
    float wv = p;
#pragma unroll
    for (int s = 0; s < SEGS; ++s) {
        wv = clampf(p, eslo[s], eshi[s]);       // thread entry in segment
        v4f r0, r1;
        wv = clampf(wv, a[s][0], a[s][0] + 1.0f); r0.x = wv;
        wv = clampf(wv, a[s][1], a[s][1] + 1.0f); r0.y = wv;
        wv = clampf(wv, a[s][2], a[s][2] + 1.0f); r0.z = wv;
        wv = clampf(wv, a[s][3], a[s][3] + 1.0f); r0.w = wv;
        wv = clampf(wv, a[s][4], a[s][4] + 1.0f); r1.x = wv;
        wv = clampf(wv, a[s][5], a[s][5] + 1.0f); r1.y = wv;
        wv = clampf(wv, a[s][6], a[s][6] + 1.0f); r1.z = wv;
        wv = clampf(wv, a[s][7], a[s][7] + 1.0f); r1.w = wv;
        v4f* o = (v4f*)(out + (size_t)b * BLK_ELEMS + (size_t)s * SEG_ELEMS)
                 + (size_t)t * 2;
        __builtin_nontemporal_store(r0, &o[0]);
        __builtin_nontemporal_store(r1, &o[1]);
        p = clampf(p, Slo[s], Shi[s]);          // advance past segment
    }

    if (b == nblocks - 1 && t == TPB - 1)
        out[(size_t)nblocks * BLK_ELEMS] = wv;  // new_state = last output
}

extern "C" void kernel_launch(void* const* d_in, const int* in_sizes, int n_in,
                              void* d_out, int out_size, void* d_ws, size_t ws_size,
                              hipStream_t stream) {
    const v4f* x4      = (const v4f*)d_in[0];      // [1,T]
    const float* state = (const float*)d_in[1];    // [1,1]
    const float* kern  = (const float*)d_in[2];    // [1,1]
    float* out = (float*)d_out;                    // T outputs + 1 new_state

    const size_t T = (size_t)in_sizes[0];
    const int nblocks = (int)(T / BLK_ELEMS);      // 1024 for T=2^23

    uint32_t* counter = (uint32_t*)d_ws;
    uint64_t* agg = (uint64_t*)((char*)d_ws + 16);

    hipMemsetAsync(d_ws, 0, 16, stream);           // zero arrive-counter only
    phi_scan<<<nblocks, TPB, 0, stream>>>(x4, kern, state, out,
                                          agg, counter, nblocks);
}

// Round 13
// 111.652 us; speedup vs baseline: 1.6659x; 1.6659x over previous
//
#include <hip/hip_runtime.h>
#include <math.h>

// out_i = clamp(out_{i-1}; a_i, a_i+1), a_i = x_i * k.  Clamp functions
// p -> min(max(p,lo),hi) compose associatively -> parallel scan.
//
// Ledger (R1-R12): bench = Sum(kernels) + ~57us harness restore/poison
// (measured fillBufferAligned dispatches inside the timed window). Spin
// barriers self-poison (R6/R12). Best family: deterministic 2-dispatch
// (R8, Sum~41us). R13: same structure, tuned for OCCUPANCY -- 16 elems
// per thread, 2048 blocks = 8 blocks/CU via __launch_bounds__(256,8)
// (VGPR<=64 -> 32 waves/CU), so scan VALU overlaps memory latency.

#define TPB 256
#define WAVES (TPB / 64)
#define PT 16                        // elems per thread (contiguous, 4x dwordx4)
#define BLK_ELEMS (TPB * PT)         // 4096 -> 2048 blocks @ T=2^23

typedef float v4f __attribute__((ext_vector_type(4)));

__device__ __forceinline__ float clampf(float x, float lo, float hi) {
    return fminf(fmaxf(x, lo), hi);
}

// ---------------- K1: per-block composed clamp aggregate ----------------
__global__ __launch_bounds__(TPB, 8) void k_agg(const v4f* __restrict__ x4,
                                                const float* __restrict__ kern,
                                                float2* __restrict__ agg) {
    __shared__ float wl[WAVES], wh[WAVES];
    const int t = threadIdx.x, lane = t & 63, w = t >> 6;
    const int b = blockIdx.x;
    const float k = kern[0];

    // thread t owns 16 contiguous floats: 4 back-to-back dwordx4 in flight
    const v4f* p = x4 + (size_t)b * (BLK_ELEMS / 4) + (size_t)t * (PT / 4);
    v4f v0 = p[0], v1 = p[1], v2 = p[2], v3 = p[3];

    float lo, hi, a;
    a = v0.x * k; lo = a; hi = a + 1.0f;
    a = v0.y * k; lo = clampf(lo, a, a + 1.0f); hi = clampf(hi, a, a + 1.0f);
    a = v0.z * k; lo = clampf(lo, a, a + 1.0f); hi = clampf(hi, a, a + 1.0f);
    a = v0.w * k; lo = clampf(lo, a, a + 1.0f); hi = clampf(hi, a, a + 1.0f);
    a = v1.x * k; lo = clampf(lo, a, a + 1.0f); hi = clampf(hi, a, a + 1.0f);
    a = v1.y * k; lo = clampf(lo, a, a + 1.0f); hi = clampf(hi, a, a + 1.0f);
    a = v1.z * k; lo = clampf(lo, a, a + 1.0f); hi = clampf(hi, a, a + 1.0f);
    a = v1.w * k; lo = clampf(lo, a, a + 1.0f); hi = clampf(hi, a, a + 1.0f);
    a = v2.x * k; lo = clampf(lo, a, a + 1.0f); hi = clampf(hi, a, a + 1.0f);
    a = v2.y * k; lo = clampf(lo, a, a + 1.0f); hi = clampf(hi, a, a + 1.0f);
    a = v2.z * k; lo = clampf(lo, a, a + 1.0f); hi = clampf(hi, a, a + 1.0f);
    a = v2.w * k; lo = clampf(lo, a, a + 1.0f); hi = clampf(hi, a, a + 1.0f);
    a = v3.x * k; lo = clampf(lo, a, a + 1.0f); hi = clampf(hi, a, a + 1.0f);
    a = v3.y * k; lo = clampf(lo, a, a + 1.0f); hi = clampf(hi, a, a + 1.0f);
    a = v3.z * k; lo = clampf(lo, a, a + 1.0f); hi = clampf(hi, a, a + 1.0f);
    a = v3.w * k; lo = clampf(lo, a, a + 1.0f); hi = clampf(hi, a, a + 1.0f);

    // ordered wave reduce: self (earlier) FIRST, lane+off (later) SECOND.
    // OOB shfl returns self; clamp-pair self-compose is identity.
#pragma unroll
    for (int off = 1; off < 64; off <<= 1) {
        float plo = __shfl_down(lo, off);
        float phi_ = __shfl_down(hi, off);
        float nlo = clampf(lo, plo, phi_);
        float nhi = clampf(hi, plo, phi_);
        lo = nlo; hi = nhi;
    }
    if (lane == 0) { wl[w] = lo; wh[w] = hi; }
    __syncthreads();
    if (t == 0) {
        float L = wl[0], H = wh[0];
#pragma unroll
        for (int i = 1; i < WAVES; ++i) {
            L = clampf(L, wl[i], wh[i]);
            H = clampf(H, wl[i], wh[i]);
        }
        agg[b] = make_float2(L, H);
    }
}

// ------- K2: entry from agg prefix, thread-serial scan, apply + write -------
__global__ __launch_bounds__(TPB, 8) void k_apply(
    const v4f* __restrict__ x4,
    const float* __restrict__ kern,
    const float* __restrict__ state,
    const float2* __restrict__ agg,
    float* __restrict__ out,          // T outputs + 1 new_state
    int nblocks)
{
    __shared__ float rl[WAVES], rh[WAVES];
    __shared__ float wtl[WAVES], wth[WAVES];
    __shared__ float s_vb;

    const int t = threadIdx.x, lane = t & 63, w = t >> 6;
    const int b = blockIdx.x;
    const float k = kern[0];

    // ---- (0) x loads first: in flight during part (A) ----
    const v4f* p = x4 + (size_t)b * (BLK_ELEMS / 4) + (size_t)t * (PT / 4);
    v4f v0 = __builtin_nontemporal_load(&p[0]);
    v4f v1 = __builtin_nontemporal_load(&p[1]);
    v4f v2 = __builtin_nontemporal_load(&p[2]);
    v4f v3 = __builtin_nontemporal_load(&p[3]);

    // ---- (A) block entry value: exclusive prefix over agg[0..b-1] ----
    {
        const int per = nblocks / TPB;   // 8
        float lo = -INFINITY, hi = INFINITY;
#pragma unroll
        for (int c = 0; c < per; ++c) {
            int j = t * per + c;
            if (j < b) {
                float2 ag = agg[j];
                lo = clampf(lo, ag.x, ag.y);
                hi = clampf(hi, ag.x, ag.y);
            }
        }
#pragma unroll
        for (int off = 1; off < 64; off <<= 1) {
            float plo = __shfl_down(lo, off);
            float phi_ = __shfl_down(hi, off);
            float nlo = clampf(lo, plo, phi_);
            float nhi = clampf(hi, plo, phi_);
            lo = nlo; hi = nhi;
        }
        if (lane == 0) { rl[w] = lo; rh[w] = hi; }
    }
    __syncthreads();
    if (t == 0) {
        float L = rl[0], H = rh[0];
#pragma unroll
        for (int i = 1; i < WAVES; ++i) {
            L = clampf(L, rl[i], rh[i]);
            H = clampf(H, rl[i], rh[i]);
        }
        s_vb = clampf(state[0], L, H);   // block entry VALUE
    }

    // ---- (B) thread-serial pair over 16 elems ----
    float a[PT];
    a[0]  = v0.x * k; a[1]  = v0.y * k; a[2]  = v0.z * k; a[3]  = v0.w * k;
    a[4]  = v1.x * k; a[5]  = v1.y * k; a[6]  = v1.z * k; a[7]  = v1.w * k;
    a[8]  = v2.x * k; a[9]  = v2.y * k; a[10] = v2.z * k; a[11] = v2.w * k;
    a[12] = v3.x * k; a[13] = v3.y * k; a[14] = v3.z * k; a[15] = v3.w * k;

    float lo = a[0], hi = a[0] + 1.0f;
#pragma unroll
    for (int j = 1; j < PT; ++j) {
        lo = clampf(lo, a[j], a[j] + 1.0f);
        hi = clampf(hi, a[j], a[j] + 1.0f);
    }

    // ---- (C) ONE wave inclusive scan on thread pairs (prefix FIRST) ----
#pragma unroll
    for (int off = 1; off < 64; off <<= 1) {
        float plo = __shfl_up(lo, off);
        float phi_ = __shfl_up(hi, off);
        if (lane >= off) {
            float nlo = clampf(plo, lo, hi);
            float nhi = clampf(phi_, lo, hi);
            lo = nlo; hi = nhi;
        }
    }
    float elo = __shfl_up(lo, 1), ehi = __shfl_up(hi, 1);  // lane-exclusive pair
    if (lane == 0) { elo = -INFINITY; ehi = INFINITY; }
    if (lane == 63) { wtl[w] = lo; wth[w] = hi; }          // wave total
    __syncthreads();

    // ---- (D) thread entry VALUE: block entry -> earlier waves -> lane-excl
    float v = s_vb;
    for (int i = 0; i < w; ++i) v = clampf(v, wtl[i], wth[i]);
    v = clampf(v, elo, ehi);

    // ---- (E) serial apply + NT stores ----
    v4f* o = (v4f*)(out + (size_t)b * BLK_ELEMS + (size_t)t * PT);
    v4f r;
    v = clampf(v, a[0],  a[0]  + 1.0f); r.x = v;
    v = clampf(v, a[1],  a[1]  + 1.0f); r.y = v;
    v = clampf(v, a[2],  a[2]  + 1.0f); r.z = v;
    v = clampf(v, a[3],  a[3]  + 1.0f); r.w = v;
    __builtin_nontemporal_store(r, &o[0]);
    v = clampf(v, a[4],  a[4]  + 1.0f); r.x = v;
    v = clampf(v, a[5],  a[5]  + 1.0f); r.y = v;
    v = clampf(v, a[6],  a[6]  + 1.0f); r.z = v;
    v = clampf(v, a[7],  a[7]  + 1.0f); r.w = v;
    __builtin_nontemporal_store(r, &o[1]);
    v = clampf(v, a[8],  a[8]  + 1.0f); r.x = v;
    v = clampf(v, a[9],  a[9]  + 1.0f); r.y = v;
    v = clampf(v, a[10], a[10] + 1.0f); r.z = v;
    v = clampf(v, a[11], a[11] + 1.0f); r.w = v;
    __builtin_nontemporal_store(r, &o[2]);
    v = clampf(v, a[12], a[12] + 1.0f); r.x = v;
    v = clampf(v, a[13], a[13] + 1.0f); r.y = v;
    v = clampf(v, a[14], a[14] + 1.0f); r.z = v;
    v = clampf(v, a[15], a[15] + 1.0f); r.w = v;
    __builtin_nontemporal_store(r, &o[3]);

    if (b == nblocks - 1 && t == TPB - 1)
        out[(size_t)nblocks * BLK_ELEMS] = v;    // new_state = last output
}

extern "C" void kernel_launch(void* const* d_in, const int* in_sizes, int n_in,
                              void* d_out, int out_size, void* d_ws, size_t ws_size,
                              hipStream_t stream) {
    const v4f* x4      = (const v4f*)d_in[0];      // [1,T]
    const float* state = (const float*)d_in[1];    // [1,1]
    const float* kern  = (const float*)d_in[2];    // [1,1]
    float* out = (float*)d_out;                    // T outputs + 1 new_state

    const size_t T = (size_t)in_sizes[0];
    const int nblocks = (int)(T / BLK_ELEMS);      // 2048 for T=2^23
    float2* agg = (float2*)d_ws;                   // fully written by K1 before K2 reads

    k_agg<<<nblocks, TPB, 0, stream>>>(x4, kern, agg);
    k_apply<<<nblocks, TPB, 0, stream>>>(x4, kern, state, agg, out, nblocks);
}